// Round 1
// baseline (181.682 us; speedup 1.0000x reference)
//
#include <hip/hip_runtime.h>
#include <hip/hip_bf16.h>

// MoE fused kernel for MI355X (gfx950).
// out[t,o] = sum_e w[t,e] * (relu(x[t]@W1[e]^T) @ W2[e]^T),
// w = softmax_e(mask( relu(x@sg1^T)@(gate_w@sg_w2)^T + x@gate_w^T ))
//
// prep_kernel: bf16-convert weights, pre-packed in MFMA B-fragment order.
// moe_kernel : 512 blocks x 512 threads (8 waves), BM=128 tokens/block.
//   - X fragments resident in VGPRs (reused by gate + all experts)
//   - per expert: G1 (X@W1^T, relu, *w) -> H in LDS (XOR-swizzled) -> G2 (H@W2^T)
//   - GEMM2 split-K over hid halves across wave pairs, LDS reduce epilogue.

typedef float f32x4 __attribute__((ext_vector_type(4)));
typedef short bf16x8 __attribute__((ext_vector_type(8)));

static __device__ __forceinline__ short f2bs(float f) {
  union { __hip_bfloat16 b; short s; } u;
  u.b = __float2bfloat16(f);
  return u.s;
}

// ws layout (shorts):
//   [0,       262144)  W1p  packed frags: (e*64 + ntile*4 + k)*512 + lane*8 + j
//   [262144,  524288)  W2p  packed frags: (e*64 + otile*8 + kstep)*512 + lane*8 + j
//   [524288,  526336)  sg1b [16][128]
//   [526336,  527360)  gwb  [8][128]
//   [527360,  527488)  gcb  [8][16]   (= gate_w @ sg_w2)

__global__ void prep_kernel(const float* __restrict__ sg_w1,
                            const float* __restrict__ sg_w2,
                            const float* __restrict__ gate_w,
                            const float* __restrict__ exp_w1,
                            const float* __restrict__ exp_w2,
                            short* __restrict__ ws_s) {
  int idx = blockIdx.x * 256 + threadIdx.x;
  if (idx < 262144) {
    int e = idx >> 15, rem = idx & 32767;
    int frag = rem >> 9, lane = (rem >> 3) & 63, j = rem & 7;
    int hid = (frag >> 2) * 16 + (lane & 15);
    int k   = (frag & 3) * 32 + (lane >> 4) * 8 + j;
    ws_s[idx] = f2bs(exp_w1[(e * 256 + hid) * 128 + k]);
  } else if (idx < 524288) {
    int i2 = idx - 262144;
    int e = i2 >> 15, rem = i2 & 32767;
    int frag = rem >> 9, lane = (rem >> 3) & 63, j = rem & 7;
    int o = (frag >> 3) * 16 + (lane & 15);
    int h = (frag & 7) * 32 + (lane >> 4) * 8 + j;
    ws_s[idx] = f2bs(exp_w2[(e * 128 + o) * 256 + h]);
  } else if (idx < 526336) {
    ws_s[idx] = f2bs(sg_w1[idx - 524288]);
  } else if (idx < 527360) {
    ws_s[idx] = f2bs(gate_w[idx - 526336]);
  } else if (idx < 527488) {
    int i = idx - 527360, e = i >> 4, j = i & 15;
    float acc = 0.f;
    for (int k = 0; k < 128; ++k) acc += gate_w[e * 128 + k] * sg_w2[k * 16 + j];
    ws_s[idx] = f2bs(acc);
  }
}

__global__ __launch_bounds__(512, 2) void moe_kernel(
    const float* __restrict__ x, const int* __restrict__ active,
    const short* __restrict__ ws_s, float* __restrict__ out) {
  __shared__ __align__(16) unsigned char smem[65536];

  const short* W1p  = ws_s;
  const short* W2p  = ws_s + 262144;
  const short* sg1b = ws_s + 524288;
  const short* gwb  = ws_s + 526336;
  const short* gcb  = ws_s + 527360;

  const int tid  = threadIdx.x;
  const int lane = tid & 63;
  const int wid  = tid >> 6;
  const int l15  = lane & 15;
  const int lg   = lane >> 4;      // 0..3
  const int wm   = wid & 1;        // token half (all phases)
  const int wn1  = wid >> 1;       // G1 hid quarter 0..3
  const int wn2  = (wid >> 1) & 1; // G2 out half
  const int wk2  = wid >> 2;       // G2 hid half (split-K)
  const int tok0 = blockIdx.x * 128;

  // gate overlay region (lives inside the H buffer, freed before expert loop)
  short* Ul   = (short*)(smem);           // [128][40] bf16, cols 16..31 zero
  short* sg1l = (short*)(smem + 10240);   // [16][136]
  short* gwl  = (short*)(smem + 14592);   // [16][136], rows 8..15 zero
  short* gcl  = (short*)(smem + 18944);   // [16][40],  pads zero

  for (int i = tid; i < 5056; i += 512) ((int*)smem)[i] = 0;
  __syncthreads();
  for (int i = tid; i < 2048; i += 512) sg1l[(i >> 7) * 136 + (i & 127)] = sg1b[i];
  for (int i = tid; i < 1024; i += 512) gwl[(i >> 7) * 136 + (i & 127)] = gwb[i];
  if (tid < 128) gcl[(tid >> 4) * 40 + (tid & 15)] = gcb[tid];

  // ---- X fragments (A-operand), resident for the whole kernel ----
  bf16x8 xf[4][4];
  {
    int trow = tok0 + wm * 64 + l15;
#pragma unroll
    for (int m = 0; m < 4; ++m) {
      const float* xr = x + (size_t)(trow + m * 16) * 128;
#pragma unroll
      for (int k = 0; k < 4; ++k) {
        int c = k * 32 + lg * 8;
        float4 a = *(const float4*)(xr + c);
        float4 b = *(const float4*)(xr + c + 4);
        bf16x8 v;
        v[0] = f2bs(a.x); v[1] = f2bs(a.y); v[2] = f2bs(a.z); v[3] = f2bs(a.w);
        v[4] = f2bs(b.x); v[5] = f2bs(b.y); v[6] = f2bs(b.z); v[7] = f2bs(b.w);
        xf[m][k] = v;
      }
    }
  }
  __syncthreads();

  // ---- gate: scores = relu(X@sg1^T)@gcomb^T + X@gw^T ; masked softmax ----
  f32x4 wreg[4];
  {
    bf16x8 bfr[4];
#pragma unroll
    for (int k = 0; k < 4; ++k)
      bfr[k] = *(const bf16x8*)(sg1l + l15 * 136 + k * 32 + lg * 8);
#pragma unroll
    for (int m = 0; m < 4; ++m) {
      f32x4 acc = {0.f, 0.f, 0.f, 0.f};
#pragma unroll
      for (int k = 0; k < 4; ++k)
        acc = __builtin_amdgcn_mfma_f32_16x16x32_bf16(xf[m][k], bfr[k], acc, 0, 0, 0);
#pragma unroll
      for (int r = 0; r < 4; ++r) {
        int tl = wm * 64 + m * 16 + lg * 4 + r;
        Ul[tl * 40 + l15] = f2bs(fmaxf(acc[r], 0.f));
      }
    }
#pragma unroll
    for (int k = 0; k < 4; ++k)
      bfr[k] = *(const bf16x8*)(gwl + l15 * 136 + k * 32 + lg * 8);
    f32x4 sc[4];
#pragma unroll
    for (int m = 0; m < 4; ++m) {
      f32x4 acc = {0.f, 0.f, 0.f, 0.f};
#pragma unroll
      for (int k = 0; k < 4; ++k)
        acc = __builtin_amdgcn_mfma_f32_16x16x32_bf16(xf[m][k], bfr[k], acc, 0, 0, 0);
      sc[m] = acc;
    }
    bf16x8 gcf = *(const bf16x8*)(gcl + l15 * 40 + lg * 8);
#pragma unroll
    for (int m = 0; m < 4; ++m) {
      int tr = wm * 64 + m * 16 + l15;
      bf16x8 uf = *(const bf16x8*)(Ul + tr * 40 + lg * 8);
      sc[m] = __builtin_amdgcn_mfma_f32_16x16x32_bf16(uf, gcf, sc[m], 0, 0, 0);
    }
    int b = tok0 >> 12;
    float am = (l15 < 8 && active[b * 8 + l15] != 0) ? 0.f : -3.0e38f;
#pragma unroll
    for (int m = 0; m < 4; ++m) {
      f32x4 w4;
#pragma unroll
      for (int r = 0; r < 4; ++r) {
        float s = sc[m][r] + am;
        float mx = s;
        mx = fmaxf(mx, __shfl_xor(mx, 1));
        mx = fmaxf(mx, __shfl_xor(mx, 2));
        mx = fmaxf(mx, __shfl_xor(mx, 4));
        float p = __expf(s - mx);
        float su = p;
        su += __shfl_xor(su, 1);
        su += __shfl_xor(su, 2);
        su += __shfl_xor(su, 4);
        w4[r] = p / su;
      }
      wreg[m] = w4;
    }
  }
  __syncthreads();  // gate overlay done; smem becomes H [128][256] bf16 (swizzled)

  f32x4 acc2[4][4];
#pragma unroll
  for (int m = 0; m < 4; ++m)
#pragma unroll
    for (int n = 0; n < 4; ++n)
      acc2[m][n] = {0.f, 0.f, 0.f, 0.f};

  for (int e = 0; e < 8; ++e) {
    float wv[4][4];
#pragma unroll
    for (int m = 0; m < 4; ++m)
#pragma unroll
      for (int r = 0; r < 4; ++r)
        wv[m][r] = __shfl(wreg[m][r], (lane & 48) | e);

    // ---- G1: H = relu(X @ W1e^T) * w, wave covers [64 tok][64 hid] ----
    const short* w1e = W1p + (e * 64 + wn1 * 16) * 512 + lane * 8;
#pragma unroll
    for (int n = 0; n < 4; ++n) {
      f32x4 a1[4];
#pragma unroll
      for (int m = 0; m < 4; ++m) a1[m] = {0.f, 0.f, 0.f, 0.f};
#pragma unroll
      for (int k = 0; k < 4; ++k) {
        bf16x8 wf = *(const bf16x8*)(w1e + (n * 4 + k) * 512);
#pragma unroll
        for (int m = 0; m < 4; ++m)
          a1[m] = __builtin_amdgcn_mfma_f32_16x16x32_bf16(xf[m][k], wf, a1[m], 0, 0, 0);
      }
      int h2 = (wn1 * 64 + n * 16 + l15) * 2;
#pragma unroll
      for (int m = 0; m < 4; ++m) {
#pragma unroll
        for (int r = 0; r < 4; ++r) {
          int tl = wm * 64 + m * 16 + lg * 4 + r;
          float v = fmaxf(a1[m][r], 0.f) * wv[m][r];
          *(short*)(smem + tl * 512 + (h2 ^ ((tl & 7) << 4))) = f2bs(v);
        }
      }
    }
    __syncthreads();

    // ---- G2: acc2 += H @ W2e^T, wave covers [64 tok][64 out] x hid-half ----
#pragma unroll
    for (int kp = 0; kp < 2; ++kp) {
      bf16x8 hf[4][2];
#pragma unroll
      for (int m = 0; m < 4; ++m) {
        int tl = wm * 64 + m * 16 + l15;
#pragma unroll
        for (int k2 = 0; k2 < 2; ++k2) {
          int h2 = (wk2 * 128 + (kp * 2 + k2) * 32 + lg * 8) * 2;
          hf[m][k2] = *(const bf16x8*)(smem + tl * 512 + (h2 ^ ((tl & 7) << 4)));
        }
      }
#pragma unroll
      for (int n = 0; n < 4; ++n) {
#pragma unroll
        for (int k2 = 0; k2 < 2; ++k2) {
          int kstep = wk2 * 4 + kp * 2 + k2;
          bf16x8 wf = *(const bf16x8*)(W2p + (e * 64 + (wn2 * 4 + n) * 8 + kstep) * 512 + lane * 8);
#pragma unroll
          for (int m = 0; m < 4; ++m)
            acc2[m][n] = __builtin_amdgcn_mfma_f32_16x16x32_bf16(hf[m][k2], wf, acc2[m][n], 0, 0, 0);
        }
      }
    }
    __syncthreads();
  }

  // ---- split-K reduce (wk2=1 -> LDS, wk2=0 adds and stores) ----
  float* hred = (float*)smem;
  if (wk2 == 1) {
#pragma unroll
    for (int m = 0; m < 4; ++m)
#pragma unroll
      for (int n = 0; n < 4; ++n)
#pragma unroll
        for (int r = 0; r < 4; ++r) {
          int tl = wm * 64 + m * 16 + lg * 4 + r;
          int o = wn2 * 64 + n * 16 + l15;
          hred[tl * 128 + o] = acc2[m][n][r];
        }
  }
  __syncthreads();
  if (wk2 == 0) {
#pragma unroll
    for (int m = 0; m < 4; ++m)
#pragma unroll
      for (int n = 0; n < 4; ++n)
#pragma unroll
        for (int r = 0; r < 4; ++r) {
          int tl = wm * 64 + m * 16 + lg * 4 + r;
          int o = wn2 * 64 + n * 16 + l15;
          out[(size_t)(tok0 + tl) * 128 + o] = acc2[m][n][r] + hred[tl * 128 + o];
        }
  }
  if (blockIdx.x == 0 && tid == 0) out[8388608] = 0.0f;  // aux_loss
}

extern "C" void kernel_launch(void* const* d_in, const int* in_sizes, int n_in,
                              void* d_out, int out_size, void* d_ws, size_t ws_size,
                              hipStream_t stream) {
  const float* x      = (const float*)d_in[0];
  const int*   act    = (const int*)d_in[1];
  const float* sg_w1  = (const float*)d_in[2];
  const float* sg_w2  = (const float*)d_in[3];
  const float* gate_w = (const float*)d_in[4];
  const float* exp_w1 = (const float*)d_in[5];
  const float* exp_w2 = (const float*)d_in[6];
  short* ws_s = (short*)d_ws;
  float* out = (float*)d_out;

  prep_kernel<<<2061, 256, 0, stream>>>(sg_w1, sg_w2, gate_w, exp_w1, exp_w2, ws_s);
  moe_kernel<<<512, 512, 0, stream>>>(x, act, ws_s, out);
}